// Round 9
// baseline (245.470 us; speedup 1.0000x reference)
//
#include <hip/hip_runtime.h>
#include <hip/hip_cooperative_groups.h>

namespace cg = cooperative_groups;

#define N_NODES 10000
#define N_EDGES 640000
#define D 128

#define BLOCKS 512        // 2 blocks/CU (coop co-resident)
#define GEMM_BLOCKS 157   // 64 nodes per block (MFMA)
#define CAP 32            // per-(row,xcd-group) capacity (mean ~8)
#define OVF_CAP 8192
#define LSTR 136          // LDS row stride in ushorts: 272B, 16B-aligned, 2-way banks
#define QPAD 272          // per-wave flat queue: 256 recs + 16 zero pad

typedef unsigned int uint32;
typedef unsigned short u16;
using short8 = __attribute__((ext_vector_type(8))) short;
using f32x4  = __attribute__((ext_vector_type(4))) float;

__device__ __forceinline__ uint32 f2bf_bits(float f) {
    uint32 u = __float_as_uint(f);
    return (u + 0x7FFFu + ((u >> 16) & 1u)) >> 16;   // RNE bf16 bits
}
__device__ __forceinline__ uint32 pack2(float lo, float hi) {
    return f2bf_bits(lo) | (f2bf_bits(hi) << 16);
}

__device__ __forceinline__ void scat_one(int r, uint32 rc, int s,
                                         int* __restrict__ cursor,
                                         uint32* __restrict__ region,
                                         int* ovf_cnt, uint2* ovf)
{
    int pos = atomicAdd(&cursor[s * N_NODES + r], 1);   // group-private cursor
    if (pos < CAP) {
        // region[row][group][CAP]: 128B cell; all writers of a cell share
        // blockIdx&7 => same XCD under round-robin mapping => local-L2 merge.
        region[(r * 8 + s) * CAP + pos] = rc;
    } else {                                   // ~never (Poisson(8) tail), correct
        int o = atomicAdd(ovf_cnt, 1);
        if (o < OVF_CAP) ovf[o] = make_uint2((uint32)r, rc);
    }
}

// One cooperative dispatch:
//   phase 0: zero cursor/ovfcnt                     (replaces memset node)
//   sync -> phase 1: MFMA GEMM (blocks<157) + scatter (all 512 blocks)
//   sync -> phase 2: wave-per-row SpMM (depth-8 pipelined gather)
__global__ void __launch_bounds__(256, 2) fused_kernel(
    const float* __restrict__ x, const float* __restrict__ w,
    const int* __restrict__ row, const int* __restrict__ col,
    const float* __restrict__ val, const float* __restrict__ bias,
    uint32* __restrict__ h2, int* __restrict__ cursor,
    int* __restrict__ ovf_cnt, uint2* __restrict__ ovf,
    uint32* __restrict__ region, float* __restrict__ out)
{
    __shared__ u16 Xs[64 * LSTR];      // 17408 B
    __shared__ u16 Ws[128 * LSTR];     // 34816 B
    __shared__ uint32 qbuf[4 * QPAD];  //  4352 B  (57 KB total, 2 blocks/CU)

    cg::grid_group grid = cg::this_grid();
    const int t = threadIdx.x;
    const int b = blockIdx.x;

    // ---- phase 0: zero cursors + ovf counter
    {
        int idx = b * 256 + t;
        if (idx < 8 * N_NODES) cursor[idx] = 0;
        else if (idx == 8 * N_NODES) *ovf_cnt = 0;
    }
    grid.sync();

    // ---- phase 1a: MFMA GEMM (blocks < 157). A[m=lane&15][k=quad*8+j];
    // B mirrors (k-major) => W staged col-major, frag = one 16B LDS read.
    // C/D: col=lane&15, row=quad*4+reg (HW-verified; absmax confirms R6-R8).
    if (b < GEMM_BLOCKS) {
        #pragma unroll
        for (int i = 0; i < 8; ++i) {                 // stage x tile (64x128)
            int lin = t + i * 256;                    // float4 index
            int rw  = lin >> 5;
            int f4  = lin & 31;
            int gr = b * 64 + rw;
            if (gr >= N_NODES) gr = N_NODES - 1;
            float4 xv = *(const float4*)&x[(size_t)gr * D + f4 * 4];
            *(uint2*)&Xs[rw * LSTR + f4 * 4] =
                make_uint2(pack2(xv.x, xv.y), pack2(xv.z, xv.w));
        }
        #pragma unroll
        for (int i = 0; i < 32; ++i) {                // stage W^T (128x128)
            int lin = t + i * 256;                    // k-pair x col index
            int c = lin & 127;
            int m = lin >> 7;
            float w0 = w[(2 * m) * D + c];
            float w1 = w[(2 * m + 1) * D + c];
            *(uint32*)&Ws[c * LSTR + 2 * m] = pack2(w0, w1);
        }
        __syncthreads();

        const int wv = t >> 6, lane = t & 63;
        const int q = lane >> 4, cl = lane & 15;
        f32x4 acc[8] = {};
        const u16* arow = &Xs[(wv * 16 + cl) * LSTR];
        #pragma unroll
        for (int k0 = 0; k0 < D; k0 += 32) {
            short8 af = *(const short8*)&arow[k0 + q * 8];
            #pragma unroll
            for (int ct = 0; ct < 8; ++ct) {
                short8 bf = *(const short8*)&Ws[(ct * 16 + cl) * LSTR + k0 + q * 8];
                acc[ct] = __builtin_amdgcn_mfma_f32_16x16x32_bf16(af, bf, acc[ct], 0, 0, 0);
            }
        }
        // h2[node*64 + c] packs cols (c, c+64): lane holds tiles ct and ct+4.
        #pragma unroll
        for (int reg = 0; reg < 4; ++reg) {
            int node = b * 64 + wv * 16 + q * 4 + reg;
            if (node < N_NODES) {
                uint32* base = h2 + (size_t)node * 64 + cl;
                #pragma unroll
                for (int ct = 0; ct < 4; ++ct)
                    base[ct * 16] = pack2(acc[ct][reg], acc[ct + 4][reg]);
            }
        }
    }

    // ---- phase 1b: scatter (all 512 blocks, ~5 edges/thread)
    {
        const int xcc = b & 7;                 // round-robin block->XCD locality
        const int tid    = b * 256 + t;
        const int stride = BLOCKS * 256;
        const int4*   row4 = (const int4*)row;
        const int4*   col4 = (const int4*)col;
        const float4* val4 = (const float4*)val;
        for (int i = tid; i < N_EDGES / 4; i += stride) {
            int4 r = row4[i]; int4 c = col4[i]; float4 v = val4[i];
            scat_one(r.x, (uint32)c.x | (f2bf_bits(v.x) << 16), xcc, cursor, region, ovf_cnt, ovf);
            scat_one(r.y, (uint32)c.y | (f2bf_bits(v.y) << 16), xcc, cursor, region, ovf_cnt, ovf);
            scat_one(r.z, (uint32)c.z | (f2bf_bits(v.z) << 16), xcc, cursor, region, ovf_cnt, ovf);
            scat_one(r.w, (uint32)c.w | (f2bf_bits(v.w) << 16), xcc, cursor, region, ovf_cnt, ovf);
        }
    }
    grid.sync();

    // ---- phase 2: SpMM, wave-per-row, depth-8 software-pipelined gather.
    {
        const int lane = t & 63;
        const int wid  = t >> 6;
        uint32* qb = &qbuf[wid * QPAD];
        const float bb0 = bias[lane];
        const float bb1 = bias[lane + 64];
        const int gw = b * 4 + wid;            // global wave id (2048 waves)
        const int novf0 = ovf_cnt[0];
        const int novf = (novf0 > OVF_CAP) ? OVF_CAP : novf0;

        for (int r = gw; r < N_NODES; r += BLOCKS * 4) {
            // preload the row's 1KB region block
            uint32 rl[4];
            #pragma unroll
            for (int i = 0; i < 4; ++i)
                rl[i] = region[r * 256 + i * 64 + lane];

            int ns[8], pref[9];
            pref[0] = 0;
            #pragma unroll
            for (int s = 0; s < 8; ++s) {
                int c = cursor[s * N_NODES + r];
                ns[s] = (c < CAP) ? c : CAP;
                pref[s + 1] = pref[s] + ns[s];
            }
            const int ntot = pref[8];

            // compact to flat LDS list: chunk i lanes<32 = seg 2i, >=32 = 2i+1
            #pragma unroll
            for (int i = 0; i < 4; ++i) {
                int p  = lane & 31;
                int hi = lane >> 5;
                int n_  = hi ? ns[2 * i + 1]   : ns[2 * i];
                int pf  = hi ? pref[2 * i + 1] : pref[2 * i];
                if (p < n_) qb[pf + p] = rl[i];
            }
            if (lane < 16) qb[ntot + lane] = 0;    // zero pad (val=+0.0 recs)
            __builtin_amdgcn_s_waitcnt(0);         // wave-local LDS drain

            const int npad = (ntot + 7) & ~7;
            float a0 = 0.f, a1 = 0.f;

            uint32 rq0,rq1,rq2,rq3,rq4,rq5,rq6,rq7;
            uint32 hh0,hh1,hh2,hh3,hh4,hh5,hh6,hh7;
            rq0 = qb[0]; hh0 = h2[((rq0 & 0xFFFFu) << 6) + lane];
            rq1 = qb[1]; hh1 = h2[((rq1 & 0xFFFFu) << 6) + lane];
            rq2 = qb[2]; hh2 = h2[((rq2 & 0xFFFFu) << 6) + lane];
            rq3 = qb[3]; hh3 = h2[((rq3 & 0xFFFFu) << 6) + lane];
            rq4 = qb[4]; hh4 = h2[((rq4 & 0xFFFFu) << 6) + lane];
            rq5 = qb[5]; hh5 = h2[((rq5 & 0xFFFFu) << 6) + lane];
            rq6 = qb[6]; hh6 = h2[((rq6 & 0xFFFFu) << 6) + lane];
            rq7 = qb[7]; hh7 = h2[((rq7 & 0xFFFFu) << 6) + lane];

#define CONSUME_PREFETCH(RQ, HH, P)                                          \
            {                                                                \
                a0 = fmaf(__uint_as_float(RQ & 0xFFFF0000u),                 \
                          __uint_as_float(HH << 16), a0);                    \
                a1 = fmaf(__uint_as_float(RQ & 0xFFFF0000u),                 \
                          __uint_as_float(HH & 0xFFFF0000u), a1);            \
                uint32 rn = qb[j + 8 + P];                                   \
                RQ = rn; HH = h2[((rn & 0xFFFFu) << 6) + lane];              \
            }

            for (int j = 0; j < npad; j += 8) {
                CONSUME_PREFETCH(rq0, hh0, 0)
                CONSUME_PREFETCH(rq1, hh1, 1)
                CONSUME_PREFETCH(rq2, hh2, 2)
                CONSUME_PREFETCH(rq3, hh3, 3)
                CONSUME_PREFETCH(rq4, hh4, 4)
                CONSUME_PREFETCH(rq5, hh5, 5)
                CONSUME_PREFETCH(rq6, hh6, 6)
                CONSUME_PREFETCH(rq7, hh7, 7)
            }
#undef CONSUME_PREFETCH

            for (int k = 0; k < novf; ++k) {       // expected empty
                uint2 e = ovf[k];
                if (e.x == (uint32)r) {
                    uint32 qq = e.y;
                    uint32 hv = h2[((qq & 0xFFFFu) << 6) + lane];
                    a0 = fmaf(__uint_as_float(qq & 0xFFFF0000u), __uint_as_float(hv << 16), a0);
                    a1 = fmaf(__uint_as_float(qq & 0xFFFF0000u), __uint_as_float(hv & 0xFFFF0000u), a1);
                }
            }

            out[(size_t)r * D + lane]      = a0 + bb0;
            out[(size_t)r * D + 64 + lane] = a1 + bb1;
        }
    }
}

extern "C" void kernel_launch(void* const* d_in, const int* in_sizes, int n_in,
                              void* d_out, int out_size, void* d_ws, size_t ws_size,
                              hipStream_t stream)
{
    const float* x    = (const float*)d_in[0];
    const float* aval = (const float*)d_in[1];
    const float* w    = (const float*)d_in[2];
    const float* bias = (const float*)d_in[3];
    const int* arow   = (const int*)d_in[4];
    const int* acol   = (const int*)d_in[5];

    char* ws = (char*)d_ws;
    uint32* h2     = (uint32*)(ws);               //  2,560,000 B
    int*    cursor = (int*)(ws + 2560000);        //    320,000 B (8 x 10000)
    int*    ovfcnt = (int*)(ws + 2880000);        //          4 B (+pad)
    uint2*  ovf    = (uint2*)(ws + 2880064);      //     65,536 B
    uint32* region = (uint32*)(ws + 2945600);     // 10,240,000 B  (~13.2 MB)
    float*  out    = (float*)d_out;

    void* args[] = { (void*)&x, (void*)&w, (void*)&arow, (void*)&acol,
                     (void*)&aval, (void*)&bias, (void*)&h2, (void*)&cursor,
                     (void*)&ovfcnt, (void*)&ovf, (void*)&region, (void*)&out };
    hipLaunchCooperativeKernel((void*)fused_kernel, dim3(BLOCKS), dim3(256),
                               args, 0, stream);
}

// Round 10
// 119.603 us; speedup vs baseline: 2.0524x; 2.0524x over previous
//
#include <hip/hip_runtime.h>

#define N_NODES 10000
#define N_EDGES 640000
#define D 128

#define GEMM_BLOCKS 157   // 64 nodes per block (MFMA)
#define TOT_BLOCKS 256    // all blocks run the scatter loop
#define CAP 32            // per-(row,xcd-group) capacity (mean ~8)
#define OVF_CAP 8192
#define LSTR 136          // LDS row stride in ushorts: 272B, 16B-aligned, 2-way banks
#define QPAD 272          // per-wave flat queue: 256 recs + 16 zero pad

typedef unsigned int uint32;
typedef unsigned short u16;
using short8 = __attribute__((ext_vector_type(8))) short;
using f32x4  = __attribute__((ext_vector_type(4))) float;

__device__ __forceinline__ uint32 f2bf_bits(float f) {
    uint32 u = __float_as_uint(f);
    return (u + 0x7FFFu + ((u >> 16) & 1u)) >> 16;   // RNE bf16 bits
}
__device__ __forceinline__ uint32 pack2(float lo, float hi) {
    return f2bf_bits(lo) | (f2bf_bits(hi) << 16);
}

__device__ __forceinline__ void scat_one(int r, uint32 rc, int s,
                                         int* __restrict__ cursor,
                                         uint32* __restrict__ region,
                                         int* ovf_cnt, uint2* ovf)
{
    // cursor r-major [r][s]: spmm reads a row's 8 counts as 2 uniform int4s.
    int pos = atomicAdd(&cursor[r * 8 + s], 1);
    if (pos < CAP) {
        // region[row][group][CAP]: 128B cell; all writers of a cell share
        // blockIdx&7 => same XCD under round-robin mapping => local-L2 merge.
        region[(r * 8 + s) * CAP + pos] = rc;
    } else {                                   // ~never (Poisson(8) tail), correct
        int o = atomicAdd(ovf_cnt, 1);
        if (o < OVF_CAP) ovf[o] = make_uint2((uint32)r, rc);
    }
}

// Fused: blocks [0,157) first do their MFMA-GEMM tile (h2 = pack_bf16(x@W),
// (c,c+64) column pairing); then ALL 256 blocks grid-stride the edge list,
// scattering into XCD-group capacity regions (group = blockIdx&7).
__global__ __launch_bounds__(256) void gemm_scatter_kernel(
    const float* __restrict__ x, const float* __restrict__ w,
    const int* __restrict__ row, const int* __restrict__ col,
    const float* __restrict__ val,
    uint32* __restrict__ h2, int* __restrict__ cursor,
    int* __restrict__ ovf_cnt, uint2* __restrict__ ovf,
    uint32* __restrict__ region)
{
    const int t = threadIdx.x;

    if (blockIdx.x < GEMM_BLOCKS) {
        // ---- MFMA GEMM: 64 rows/block, 4 waves x 16 rows x 128 cols.
        // A[m=lane&15][k=quad*8+j]; B mirrors (k-major per lane) => W staged
        // col-major, each frag one 16B LDS read. C/D: col=lane&15,
        // row=quad*4+reg (HW-verified m89/m91; absmax confirms R6-R8).
        __shared__ u16 Xs[64 * LSTR];    // 17408 B, bf16 row-major
        __shared__ u16 Ws[128 * LSTR];   // 34816 B, bf16 col-major Ws[c*LSTR+k]

        #pragma unroll
        for (int i = 0; i < 8; ++i) {                 // stage x tile (64x128)
            int lin = t + i * 256;                    // float4 index
            int rw  = lin >> 5;
            int f4  = lin & 31;
            int gr = blockIdx.x * 64 + rw;
            if (gr >= N_NODES) gr = N_NODES - 1;
            float4 xv = *(const float4*)&x[(size_t)gr * D + f4 * 4];
            *(uint2*)&Xs[rw * LSTR + f4 * 4] =
                make_uint2(pack2(xv.x, xv.y), pack2(xv.z, xv.w));
        }
        #pragma unroll
        for (int i = 0; i < 32; ++i) {                // stage W^T (128x128)
            int lin = t + i * 256;                    // k-pair x col index
            int c = lin & 127;
            int m = lin >> 7;
            float w0 = w[(2 * m) * D + c];
            float w1 = w[(2 * m + 1) * D + c];
            *(uint32*)&Ws[c * LSTR + 2 * m] = pack2(w0, w1);
        }
        __syncthreads();

        const int wv = t >> 6, lane = t & 63;
        const int q = lane >> 4, cl = lane & 15;
        f32x4 acc[8] = {};
        const u16* arow = &Xs[(wv * 16 + cl) * LSTR];
        #pragma unroll
        for (int k0 = 0; k0 < D; k0 += 32) {
            short8 af = *(const short8*)&arow[k0 + q * 8];
            #pragma unroll
            for (int ct = 0; ct < 8; ++ct) {
                short8 bf = *(const short8*)&Ws[(ct * 16 + cl) * LSTR + k0 + q * 8];
                acc[ct] = __builtin_amdgcn_mfma_f32_16x16x32_bf16(af, bf, acc[ct], 0, 0, 0);
            }
        }
        // h2[node*64 + c] packs cols (c, c+64): same lane holds tiles ct, ct+4.
        #pragma unroll
        for (int reg = 0; reg < 4; ++reg) {
            int node = blockIdx.x * 64 + wv * 16 + q * 4 + reg;
            if (node < N_NODES) {
                uint32* base = h2 + (size_t)node * 64 + cl;
                #pragma unroll
                for (int ct = 0; ct < 4; ++ct)
                    base[ct * 16] = pack2(acc[ct][reg], acc[ct + 4][reg]);
            }
        }
    }

    // ---- Scatter (all blocks): ~10 edges/thread grid-stride.
    {
        const int xcc = blockIdx.x & 7;     // round-robin block->XCD locality
        const int tid    = blockIdx.x * 256 + t;
        const int stride = TOT_BLOCKS * 256;
        const int4*   row4 = (const int4*)row;
        const int4*   col4 = (const int4*)col;
        const float4* val4 = (const float4*)val;
        for (int i = tid; i < N_EDGES / 4; i += stride) {
            int4 r = row4[i]; int4 c = col4[i]; float4 v = val4[i];
            scat_one(r.x, (uint32)c.x | (f2bf_bits(v.x) << 16), xcc, cursor, region, ovf_cnt, ovf);
            scat_one(r.y, (uint32)c.y | (f2bf_bits(v.y) << 16), xcc, cursor, region, ovf_cnt, ovf);
            scat_one(r.z, (uint32)c.z | (f2bf_bits(v.z) << 16), xcc, cursor, region, ovf_cnt, ovf);
            scat_one(r.w, (uint32)c.w | (f2bf_bits(v.w) << 16), xcc, cursor, region, ovf_cnt, ovf);
        }
    }
}

// Wave-per-row SpMM. Counts via 2 wave-uniform int4 loads; region preload is
// PREDICATED (only occupied head slots of each 128B cell are fetched) and
// fused with LDS compaction; then branch-free depth-8 software-pipelined
// gather (8 L2 gathers always in flight). Zero-pad recs => no inner branches.
__global__ __launch_bounds__(256) void spmm_kernel(
    const uint32* __restrict__ region, const int* __restrict__ cursor,
    const int* __restrict__ ovf_cnt, const uint2* __restrict__ ovf,
    const uint32* __restrict__ h2, const float* __restrict__ bias,
    float* __restrict__ out)
{
    __shared__ uint32 qbuf[4 * QPAD];     // per-wave flat queues (4352 B)
    const int t = threadIdx.x;
    const int lane = t & 63;
    const int wid  = t >> 6;
    const int r = blockIdx.x * 4 + wid;
    uint32* qb = &qbuf[wid * QPAD];

    // counts (r-major): two uniform 16B loads, broadcast to all lanes
    int4 c0 = *(const int4*)&cursor[r * 8];
    int4 c1 = *(const int4*)&cursor[r * 8 + 4];
    int ns[8], pref[9];
    ns[0]=c0.x; ns[1]=c0.y; ns[2]=c0.z; ns[3]=c0.w;
    ns[4]=c1.x; ns[5]=c1.y; ns[6]=c1.z; ns[7]=c1.w;
    pref[0] = 0;
    #pragma unroll
    for (int s = 0; s < 8; ++s) {
        ns[s] = (ns[s] < CAP) ? ns[s] : CAP;
        pref[s + 1] = pref[s] + ns[s];
    }
    const int ntot = pref[8];

    // predicated load + compact: chunk i lanes<32 = seg 2i, lanes>=32 = 2i+1
    #pragma unroll
    for (int i = 0; i < 4; ++i) {
        int p  = lane & 31;
        int hi = lane >> 5;
        int n_  = hi ? ns[2 * i + 1]   : ns[2 * i];
        int pf  = hi ? pref[2 * i + 1] : pref[2 * i];
        if (p < n_) {
            uint32 v = region[r * 256 + i * 64 + lane];
            qb[pf + p] = v;
        }
    }
    if (lane < 16) qb[ntot + lane] = 0;    // zero pad (val=+0.0 recs)
    __builtin_amdgcn_s_waitcnt(0);         // wave-local drain of LDS writes

    const int npad = (ntot + 7) & ~7;
    float a0 = 0.f, a1 = 0.f;

    uint32 rq0,rq1,rq2,rq3,rq4,rq5,rq6,rq7;
    uint32 hh0,hh1,hh2,hh3,hh4,hh5,hh6,hh7;
    rq0 = qb[0]; hh0 = h2[((rq0 & 0xFFFFu) << 6) + lane];
    rq1 = qb[1]; hh1 = h2[((rq1 & 0xFFFFu) << 6) + lane];
    rq2 = qb[2]; hh2 = h2[((rq2 & 0xFFFFu) << 6) + lane];
    rq3 = qb[3]; hh3 = h2[((rq3 & 0xFFFFu) << 6) + lane];
    rq4 = qb[4]; hh4 = h2[((rq4 & 0xFFFFu) << 6) + lane];
    rq5 = qb[5]; hh5 = h2[((rq5 & 0xFFFFu) << 6) + lane];
    rq6 = qb[6]; hh6 = h2[((rq6 & 0xFFFFu) << 6) + lane];
    rq7 = qb[7]; hh7 = h2[((rq7 & 0xFFFFu) << 6) + lane];

#define CONSUME_PREFETCH(RQ, HH, P)                                          \
    {                                                                        \
        a0 = fmaf(__uint_as_float(RQ & 0xFFFF0000u),                         \
                  __uint_as_float(HH << 16), a0);                            \
        a1 = fmaf(__uint_as_float(RQ & 0xFFFF0000u),                         \
                  __uint_as_float(HH & 0xFFFF0000u), a1);                    \
        uint32 rn = qb[j + 8 + P];                                           \
        RQ = rn; HH = h2[((rn & 0xFFFFu) << 6) + lane];                      \
    }

    for (int j = 0; j < npad; j += 8) {
        CONSUME_PREFETCH(rq0, hh0, 0)
        CONSUME_PREFETCH(rq1, hh1, 1)
        CONSUME_PREFETCH(rq2, hh2, 2)
        CONSUME_PREFETCH(rq3, hh3, 3)
        CONSUME_PREFETCH(rq4, hh4, 4)
        CONSUME_PREFETCH(rq5, hh5, 5)
        CONSUME_PREFETCH(rq6, hh6, 6)
        CONSUME_PREFETCH(rq7, hh7, 7)
    }
#undef CONSUME_PREFETCH

    // overflow list (expected empty)
    int novf = ovf_cnt[0];
    if (novf > OVF_CAP) novf = OVF_CAP;
    for (int k = 0; k < novf; ++k) {
        uint2 e = ovf[k];
        if (e.x == (uint32)r) {
            uint32 qq = e.y;
            uint32 hv = h2[((qq & 0xFFFFu) << 6) + lane];
            a0 = fmaf(__uint_as_float(qq & 0xFFFF0000u), __uint_as_float(hv << 16), a0);
            a1 = fmaf(__uint_as_float(qq & 0xFFFF0000u), __uint_as_float(hv & 0xFFFF0000u), a1);
        }
    }

    out[(size_t)r * D + lane]      = a0 + bias[lane];
    out[(size_t)r * D + 64 + lane] = a1 + bias[lane + 64];
}

extern "C" void kernel_launch(void* const* d_in, const int* in_sizes, int n_in,
                              void* d_out, int out_size, void* d_ws, size_t ws_size,
                              hipStream_t stream)
{
    const float* x    = (const float*)d_in[0];
    const float* aval = (const float*)d_in[1];
    const float* w    = (const float*)d_in[2];
    const float* bias = (const float*)d_in[3];
    const int* arow   = (const int*)d_in[4];
    const int* acol   = (const int*)d_in[5];

    char* ws = (char*)d_ws;
    uint32* h2     = (uint32*)(ws);               //  2,560,000 B
    int*    cursor = (int*)(ws + 2560000);        //    320,000 B (10000 x 8)
    int*    ovfcnt = (int*)(ws + 2880000);        //          4 B (+pad)
    uint2*  ovf    = (uint2*)(ws + 2880064);      //     65,536 B
    uint32* region = (uint32*)(ws + 2945600);     // 10,240,000 B  (~13.2 MB)

    hipMemsetAsync(ws + 2560000, 0, 320004, stream);  // cursor + ovf_cnt

    gemm_scatter_kernel<<<TOT_BLOCKS, 256, 0, stream>>>(
        x, w, arow, acol, aval, h2, cursor, ovfcnt, ovf, region);
    spmm_kernel<<<N_NODES / 4, 256, 0, stream>>>(
        region, cursor, ovfcnt, ovf, h2, bias, (float*)d_out);
}

// Round 11
// 116.305 us; speedup vs baseline: 2.1106x; 1.0284x over previous
//
#include <hip/hip_runtime.h>

#define N_NODES 10000
#define N_EDGES 640000
#define D 128

#define GEMM_BLOCKS 157   // 64 nodes per block (MFMA)
#define TOT_BLOCKS 256
#define NSLOTS 355        // 157 gemm blocks x1 + 99 scatter blocks x2
#define CAP 32            // per-(row,xcd-group) capacity (mean ~8)
#define OVF_CAP 8192
#define LSTR 136          // LDS row stride in ushorts: 272B, 16B-aligned, 2-way banks
#define QPAD 272          // per-wave flat queue: 256 recs + 16 zero pad

typedef unsigned int uint32;
typedef unsigned short u16;
using short8 = __attribute__((ext_vector_type(8))) short;
using f32x4  = __attribute__((ext_vector_type(4))) float;

__device__ __forceinline__ uint32 f2bf_bits(float f) {
    uint32 u = __float_as_uint(f);
    return (u + 0x7FFFu + ((u >> 16) & 1u)) >> 16;   // RNE bf16 bits
}
__device__ __forceinline__ uint32 pack2(float lo, float hi) {
    return f2bf_bits(lo) | (f2bf_bits(hi) << 16);
}

__device__ __forceinline__ void scat_one(int r, uint32 rc, int s,
                                         int* __restrict__ cursor,
                                         uint32* __restrict__ region,
                                         int* ovf_cnt, uint2* ovf)
{
    // cursor s-major: each XCD-group's counters live in a private 40KB range
    // (line-exclusive per XCD -> no cross-XCD line ping-pong; R10 showed the
    // r-major variant regresses).
    int pos = atomicAdd(&cursor[s * N_NODES + r], 1);
    if (pos < CAP) {
        // region[row][group][CAP]: 128B cell; all writers of a cell share
        // blockIdx&7 => same XCD under round-robin mapping => local-L2 merge.
        region[(r * 8 + s) * CAP + pos] = rc;
    } else {                                   // ~never (Poisson(8) tail), correct
        int o = atomicAdd(ovf_cnt, 1);
        if (o < OVF_CAP) ovf[o] = make_uint2((uint32)r, rc);
    }
}

__device__ __forceinline__ void scat_slot(int slot, int t, int xcc,
                                          const int4* row4, const int4* col4,
                                          const float4* val4,
                                          int* cursor, uint32* region,
                                          int* ovf_cnt, uint2* ovf)
{
    for (int i = slot * 256 + t; i < N_EDGES / 4; i += NSLOTS * 256) {
        int4 r = row4[i]; int4 c = col4[i]; float4 v = val4[i];
        scat_one(r.x, (uint32)c.x | (f2bf_bits(v.x) << 16), xcc, cursor, region, ovf_cnt, ovf);
        scat_one(r.y, (uint32)c.y | (f2bf_bits(v.y) << 16), xcc, cursor, region, ovf_cnt, ovf);
        scat_one(r.z, (uint32)c.z | (f2bf_bits(v.z) << 16), xcc, cursor, region, ovf_cnt, ovf);
        scat_one(r.w, (uint32)c.w | (f2bf_bits(v.w) << 16), xcc, cursor, region, ovf_cnt, ovf);
    }
}

// Fused: blocks [0,157) do their MFMA-GEMM tile then 1 scatter slot; blocks
// [157,256) do 2 scatter slots (weighted split so gemm+scatter and
// scatter-only blocks finish together).
__global__ __launch_bounds__(256) void gemm_scatter_kernel(
    const float* __restrict__ x, const float* __restrict__ w,
    const int* __restrict__ row, const int* __restrict__ col,
    const float* __restrict__ val,
    uint32* __restrict__ h2, int* __restrict__ cursor,
    int* __restrict__ ovf_cnt, uint2* __restrict__ ovf,
    uint32* __restrict__ region)
{
    const int t = threadIdx.x;
    const int b = blockIdx.x;
    const int xcc = b & 7;                  // round-robin block->XCD locality
    const int4*   row4 = (const int4*)row;
    const int4*   col4 = (const int4*)col;
    const float4* val4 = (const float4*)val;

    if (b < GEMM_BLOCKS) {
        // ---- MFMA GEMM: 64 rows/block, 4 waves x 16 rows x 128 cols.
        // A[m=lane&15][k=quad*8+j]; B mirrors (k-major per lane) => W staged
        // col-major, each frag one 16B LDS read. C/D: col=lane&15,
        // row=quad*4+reg (HW-verified m89/m91; absmax confirms R6-R10).
        __shared__ u16 Xs[64 * LSTR];    // 17408 B, bf16 row-major
        __shared__ u16 Ws[128 * LSTR];   // 34816 B, bf16 col-major Ws[c*LSTR+k]

        #pragma unroll
        for (int i = 0; i < 8; ++i) {                 // stage x tile (64x128)
            int lin = t + i * 256;                    // float4 index
            int rw  = lin >> 5;
            int f4  = lin & 31;
            int gr = b * 64 + rw;
            if (gr >= N_NODES) gr = N_NODES - 1;
            float4 xv = *(const float4*)&x[(size_t)gr * D + f4 * 4];
            *(uint2*)&Xs[rw * LSTR + f4 * 4] =
                make_uint2(pack2(xv.x, xv.y), pack2(xv.z, xv.w));
        }
        #pragma unroll
        for (int i = 0; i < 32; ++i) {                // stage W^T (128x128)
            int lin = t + i * 256;                    // k-pair x col index
            int c = lin & 127;
            int m = lin >> 7;
            float w0 = w[(2 * m) * D + c];
            float w1 = w[(2 * m + 1) * D + c];
            *(uint32*)&Ws[c * LSTR + 2 * m] = pack2(w0, w1);
        }
        __syncthreads();

        const int wv = t >> 6, lane = t & 63;
        const int q = lane >> 4, cl = lane & 15;
        f32x4 acc[8] = {};
        const u16* arow = &Xs[(wv * 16 + cl) * LSTR];
        #pragma unroll
        for (int k0 = 0; k0 < D; k0 += 32) {
            short8 af = *(const short8*)&arow[k0 + q * 8];
            #pragma unroll
            for (int ct = 0; ct < 8; ++ct) {
                short8 bf = *(const short8*)&Ws[(ct * 16 + cl) * LSTR + k0 + q * 8];
                acc[ct] = __builtin_amdgcn_mfma_f32_16x16x32_bf16(af, bf, acc[ct], 0, 0, 0);
            }
        }
        // h2[node*64 + c] packs cols (c, c+64): same lane holds tiles ct, ct+4.
        #pragma unroll
        for (int reg = 0; reg < 4; ++reg) {
            int node = b * 64 + wv * 16 + q * 4 + reg;
            if (node < N_NODES) {
                uint32* base = h2 + (size_t)node * 64 + cl;
                #pragma unroll
                for (int ct = 0; ct < 4; ++ct)
                    base[ct * 16] = pack2(acc[ct][reg], acc[ct + 4][reg]);
            }
        }
        // one scatter slot
        scat_slot(b, t, xcc, row4, col4, val4, cursor, region, ovf_cnt, ovf);
    } else {
        // two scatter slots
        int s0 = 2 * b - GEMM_BLOCKS;       // 157 + 2*(b-157)
        scat_slot(s0,     t, xcc, row4, col4, val4, cursor, region, ovf_cnt, ovf);
        scat_slot(s0 + 1, t, xcc, row4, col4, val4, cursor, region, ovf_cnt, ovf);
    }
}

// Wave-per-row SpMM (R8-verified): preload the row's 1KB region block, 8
// scalar count loads, LDS compaction, then branch-free depth-8
// software-pipelined gather (8 L2 gathers always in flight).
__global__ __launch_bounds__(256) void spmm_kernel(
    const uint32* __restrict__ region, const int* __restrict__ cursor,
    const int* __restrict__ ovf_cnt, const uint2* __restrict__ ovf,
    const uint32* __restrict__ h2, const float* __restrict__ bias,
    float* __restrict__ out)
{
    __shared__ uint32 qbuf[4 * QPAD];     // per-wave flat queues (4352 B)
    const int t = threadIdx.x;
    const int lane = t & 63;
    const int wid  = t >> 6;
    const int r = blockIdx.x * 4 + wid;
    uint32* qb = &qbuf[wid * QPAD];

    // preload the row's 1KB region block (segment s = cell>>5, pos = cell&31)
    uint32 rl[4];
    #pragma unroll
    for (int i = 0; i < 4; ++i)
        rl[i] = region[r * 256 + i * 64 + lane];

    // counts + prefix (wave-uniform scalar loads, one per group range)
    int ns[8], pref[9];
    pref[0] = 0;
    #pragma unroll
    for (int s = 0; s < 8; ++s) {
        int c = cursor[s * N_NODES + r];
        ns[s] = (c < CAP) ? c : CAP;
        pref[s + 1] = pref[s] + ns[s];
    }
    const int ntot = pref[8];

    // compact to flat LDS list: chunk i lanes<32 = seg 2i, lanes>=32 = 2i+1
    #pragma unroll
    for (int i = 0; i < 4; ++i) {
        int p  = lane & 31;
        int hi = lane >> 5;
        int n_  = hi ? ns[2 * i + 1]   : ns[2 * i];
        int pf  = hi ? pref[2 * i + 1] : pref[2 * i];
        if (p < n_) qb[pf + p] = rl[i];
    }
    if (lane < 16) qb[ntot + lane] = 0;    // zero pad (val=+0.0 recs)
    __builtin_amdgcn_s_waitcnt(0);         // wave-local drain of LDS writes

    const int npad = (ntot + 7) & ~7;
    float a0 = 0.f, a1 = 0.f;

    uint32 rq0,rq1,rq2,rq3,rq4,rq5,rq6,rq7;
    uint32 hh0,hh1,hh2,hh3,hh4,hh5,hh6,hh7;
    rq0 = qb[0]; hh0 = h2[((rq0 & 0xFFFFu) << 6) + lane];
    rq1 = qb[1]; hh1 = h2[((rq1 & 0xFFFFu) << 6) + lane];
    rq2 = qb[2]; hh2 = h2[((rq2 & 0xFFFFu) << 6) + lane];
    rq3 = qb[3]; hh3 = h2[((rq3 & 0xFFFFu) << 6) + lane];
    rq4 = qb[4]; hh4 = h2[((rq4 & 0xFFFFu) << 6) + lane];
    rq5 = qb[5]; hh5 = h2[((rq5 & 0xFFFFu) << 6) + lane];
    rq6 = qb[6]; hh6 = h2[((rq6 & 0xFFFFu) << 6) + lane];
    rq7 = qb[7]; hh7 = h2[((rq7 & 0xFFFFu) << 6) + lane];

#define CONSUME_PREFETCH(RQ, HH, P)                                          \
    {                                                                        \
        a0 = fmaf(__uint_as_float(RQ & 0xFFFF0000u),                         \
                  __uint_as_float(HH << 16), a0);                            \
        a1 = fmaf(__uint_as_float(RQ & 0xFFFF0000u),                         \
                  __uint_as_float(HH & 0xFFFF0000u), a1);                    \
        uint32 rn = qb[j + 8 + P];                                           \
        RQ = rn; HH = h2[((rn & 0xFFFFu) << 6) + lane];                      \
    }

    for (int j = 0; j < npad; j += 8) {
        CONSUME_PREFETCH(rq0, hh0, 0)
        CONSUME_PREFETCH(rq1, hh1, 1)
        CONSUME_PREFETCH(rq2, hh2, 2)
        CONSUME_PREFETCH(rq3, hh3, 3)
        CONSUME_PREFETCH(rq4, hh4, 4)
        CONSUME_PREFETCH(rq5, hh5, 5)
        CONSUME_PREFETCH(rq6, hh6, 6)
        CONSUME_PREFETCH(rq7, hh7, 7)
    }
#undef CONSUME_PREFETCH

    // overflow list (expected empty)
    int novf = ovf_cnt[0];
    if (novf > OVF_CAP) novf = OVF_CAP;
    for (int k = 0; k < novf; ++k) {
        uint2 e = ovf[k];
        if (e.x == (uint32)r) {
            uint32 qq = e.y;
            uint32 hv = h2[((qq & 0xFFFFu) << 6) + lane];
            a0 = fmaf(__uint_as_float(qq & 0xFFFF0000u), __uint_as_float(hv << 16), a0);
            a1 = fmaf(__uint_as_float(qq & 0xFFFF0000u), __uint_as_float(hv & 0xFFFF0000u), a1);
        }
    }

    out[(size_t)r * D + lane]      = a0 + bias[lane];
    out[(size_t)r * D + 64 + lane] = a1 + bias[lane + 64];
}

extern "C" void kernel_launch(void* const* d_in, const int* in_sizes, int n_in,
                              void* d_out, int out_size, void* d_ws, size_t ws_size,
                              hipStream_t stream)
{
    const float* x    = (const float*)d_in[0];
    const float* aval = (const float*)d_in[1];
    const float* w    = (const float*)d_in[2];
    const float* bias = (const float*)d_in[3];
    const int* arow   = (const int*)d_in[4];
    const int* acol   = (const int*)d_in[5];

    char* ws = (char*)d_ws;
    uint32* h2     = (uint32*)(ws);               //  2,560,000 B
    int*    cursor = (int*)(ws + 2560000);        //    320,000 B (8 x 10000)
    int*    ovfcnt = (int*)(ws + 2880000);        //          4 B (+pad)
    uint2*  ovf    = (uint2*)(ws + 2880064);      //     65,536 B
    uint32* region = (uint32*)(ws + 2945600);     // 10,240,000 B  (~13.2 MB)

    hipMemsetAsync(ws + 2560000, 0, 320004, stream);  // cursor + ovf_cnt

    gemm_scatter_kernel<<<TOT_BLOCKS, 256, 0, stream>>>(
        x, w, arow, acol, aval, h2, cursor, ovfcnt, ovf, region);
    spmm_kernel<<<N_NODES / 4, 256, 0, stream>>>(
        region, cursor, ovfcnt, ovf, h2, bias, (float*)d_out);
}